// Round 1
// baseline (2929.930 us; speedup 1.0000x reference)
//
#include <hip/hip_runtime.h>
#include <math.h>

// Problem constants
#define T_LEN  256
#define BATCH  32
#define EMBD   256
#define HHD    256           // per-direction hidden
#define NTAGS  12
#define NEGV   (-10000.0f)

// ---------------------------------------------------------------------------
// Kernel 1: zx = gather(embed)[m,:] @ [W_ih_f | W_ih_b]^T + bias
// M = 8192 rows (m = t*32 + b), N = 2048 (n<1024: fwd gate-row n, else bwd),
// K = 256. Tiled 128x128x16, 256 threads, 8x8 micro-tile per thread.
// zx layout: [8192][2048] fp32.
// ---------------------------------------------------------------------------
__global__ __launch_bounds__(256) void gemm_zx(
    const int* __restrict__ sentence, const float* __restrict__ embed,
    const float* __restrict__ Wf,  const float* __restrict__ Wb,
    const float* __restrict__ bf,  const float* __restrict__ bb,
    float* __restrict__ zx)
{
    __shared__ float As[16][132];   // [k][m], pad 132 -> 2-way bank alias only (free)
    __shared__ float Bs[16][132];   // [k][n]

    const int tid = threadIdx.x;
    const int tx = tid & 15, ty = tid >> 4;
    const int Mbase = (int)(blockIdx.x >> 4) * 128;   // 64 M-tiles
    const int Nbase = (int)(blockIdx.x & 15) * 128;   // 16 N-tiles (tile never crosses dir boundary at 1024)

    const float* Wsrc = (Nbase < 1024) ? Wf : Wb;
    const float* bsrc = (Nbase < 1024) ? bf : bb;
    const int nOff = (Nbase < 1024) ? Nbase : (Nbase - 1024);

    // Each thread stages 2 float4 of A and 2 of B per K-tile; its rows are fixed.
    const int m0 = tid >> 2;              // 0..63
    const int m1 = m0 + 64;
    const int kq = (tid & 3) * 4;         // k offset within 16-wide K-tile
    const int mg0 = Mbase + m0, mg1 = Mbase + m1;
    // token for row m: t = m/32, b = m%32, sentence is [B][T]
    const int tok0 = sentence[(mg0 & 31) * T_LEN + (mg0 >> 5)];
    const int tok1 = sentence[(mg1 & 31) * T_LEN + (mg1 >> 5)];
    const float* arow0 = embed + (long long)tok0 * EMBD;
    const float* arow1 = embed + (long long)tok1 * EMBD;
    const float* brow0 = Wsrc + (long long)(nOff + m0) * EMBD;
    const float* brow1 = Wsrc + (long long)(nOff + m1) * EMBD;

    float acc[8][8];
#pragma unroll
    for (int i = 0; i < 8; ++i)
#pragma unroll
        for (int j = 0; j < 8; ++j) acc[i][j] = 0.0f;

    for (int k0 = 0; k0 < EMBD; k0 += 16) {
        float4 av0 = *(const float4*)(arow0 + k0 + kq);
        float4 av1 = *(const float4*)(arow1 + k0 + kq);
        float4 bv0 = *(const float4*)(brow0 + k0 + kq);
        float4 bv1 = *(const float4*)(brow1 + k0 + kq);
        __syncthreads();
        As[kq+0][m0] = av0.x; As[kq+1][m0] = av0.y; As[kq+2][m0] = av0.z; As[kq+3][m0] = av0.w;
        As[kq+0][m1] = av1.x; As[kq+1][m1] = av1.y; As[kq+2][m1] = av1.z; As[kq+3][m1] = av1.w;
        Bs[kq+0][m0] = bv0.x; Bs[kq+1][m0] = bv0.y; Bs[kq+2][m0] = bv0.z; Bs[kq+3][m0] = bv0.w;
        Bs[kq+0][m1] = bv1.x; Bs[kq+1][m1] = bv1.y; Bs[kq+2][m1] = bv1.z; Bs[kq+3][m1] = bv1.w;
        __syncthreads();
#pragma unroll
        for (int kt = 0; kt < 16; ++kt) {
            float am[8], bn[8];
            *(float4*)&am[0] = *(const float4*)&As[kt][ty * 4];
            *(float4*)&am[4] = *(const float4*)&As[kt][64 + ty * 4];
            *(float4*)&bn[0] = *(const float4*)&Bs[kt][tx * 4];
            *(float4*)&bn[4] = *(const float4*)&Bs[kt][64 + tx * 4];
#pragma unroll
            for (int i = 0; i < 8; ++i)
#pragma unroll
                for (int j = 0; j < 8; ++j) acc[i][j] += am[i] * bn[j];
        }
    }

    float4 bias0 = *(const float4*)(bsrc + nOff + tx * 4);
    float4 bias1 = *(const float4*)(bsrc + nOff + 64 + tx * 4);
    const float bnv[8] = {bias0.x, bias0.y, bias0.z, bias0.w,
                          bias1.x, bias1.y, bias1.z, bias1.w};
#pragma unroll
    for (int i = 0; i < 8; ++i) {
        const int mg = Mbase + ty * 4 + (i & 3) + ((i >= 4) ? 64 : 0);
        float4 o0 = make_float4(acc[i][0] + bnv[0], acc[i][1] + bnv[1],
                                acc[i][2] + bnv[2], acc[i][3] + bnv[3]);
        float4 o1 = make_float4(acc[i][4] + bnv[4], acc[i][5] + bnv[5],
                                acc[i][6] + bnv[6], acc[i][7] + bnv[7]);
        *(float4*)(zx + (long long)mg * 2048 + Nbase + tx * 4) = o0;
        *(float4*)(zx + (long long)mg * 2048 + Nbase + 64 + tx * 4) = o1;
    }
}

// ---------------------------------------------------------------------------
// Kernel 2 (launched 256x): one LSTM time step, both directions.
// Grid = 64 WGs: bx>>5 = dir d, (bx&31)*8 = e0 (h-element block of 8).
// WG owns gate rows {g*256 + e0 + i : g in 0..3, i in 0..7} (32 rows),
// computes z[32b][32r] (K=256 over h_prev), then gates + state update.
// hbuf ping-pongs by step parity; cbuf updated in place (exclusive owner).
// ---------------------------------------------------------------------------
__global__ __launch_bounds__(256) void lstm_step(
    const int s,
    const float* __restrict__ zx,
    const float* __restrict__ Whf, const float* __restrict__ Whb,
    const float* __restrict__ h0,  const float* __restrict__ c0,
    float* __restrict__ hbuf, float* __restrict__ cbuf,
    float* __restrict__ lstm_out)
{
    __shared__ float hS[32][132];   // h_prev [b][k-half]
    __shared__ float wS[32][132];   // W_hh rows [r][k-half]
    __shared__ float zS[32][36];    // z outputs [b][r]

    const int tid = threadIdx.x;
    const int d  = blockIdx.x >> 5;
    const int e0 = (blockIdx.x & 31) * 8;
    const int t  = d ? (T_LEN - 1 - s) : s;
    const float* Wh = d ? Whb : Whf;
    const float* hsrc = (s == 0) ? (h0 + d * BATCH * HHD)
                                 : (hbuf + (((s & 1) * 2 + d) * BATCH * HHD));
    float* hdst = hbuf + ((((s & 1) ^ 1) * 2 + d) * BATCH * HHD);

    const int tx = tid & 15, ty = tid >> 4;
    const int b0 = tx, b1 = tx + 16;
    const int r0 = ty, r1 = ty + 16;
    const int grow0 = ((r0 >> 3) * 256) + e0 + (r0 & 7);
    const int grow1 = ((r1 >> 3) * 256) + e0 + (r1 & 7);

    // init accumulators from zx (input projection + bias)
    const long long zr0 = (long long)(t * BATCH + b0) * 2048 + d * 1024;
    const long long zr1 = (long long)(t * BATCH + b1) * 2048 + d * 1024;
    float a00 = zx[zr0 + grow0], a01 = zx[zr0 + grow1];
    float a10 = zx[zr1 + grow0], a11 = zx[zr1 + grow1];

    for (int ph = 0; ph < 2; ++ph) {
        const int k0 = ph * 128;
        __syncthreads();
#pragma unroll
        for (int i = 0; i < 4; ++i) {
            const int idx = tid + i * 256;        // 0..1023 float4 slots
            const int bb = idx >> 5;              // row (b or r) 0..31
            const int k4 = (idx & 31) * 4;        // k within half
            *(float4*)&hS[bb][k4] = *(const float4*)(hsrc + bb * HHD + k0 + k4);
            const int grw = ((bb >> 3) * 256) + e0 + (bb & 7);
            *(float4*)&wS[bb][k4] = *(const float4*)(Wh + (long long)grw * HHD + k0 + k4);
        }
        __syncthreads();
#pragma unroll
        for (int kk = 0; kk < 128; kk += 4) {
            float4 hv0 = *(const float4*)&hS[b0][kk];
            float4 hv1 = *(const float4*)&hS[b1][kk];
            float4 wv0 = *(const float4*)&wS[r0][kk];
            float4 wv1 = *(const float4*)&wS[r1][kk];
            a00 += hv0.x*wv0.x + hv0.y*wv0.y + hv0.z*wv0.z + hv0.w*wv0.w;
            a01 += hv0.x*wv1.x + hv0.y*wv1.y + hv0.z*wv1.z + hv0.w*wv1.w;
            a10 += hv1.x*wv0.x + hv1.y*wv0.y + hv1.z*wv0.z + hv1.w*wv0.w;
            a11 += hv1.x*wv1.x + hv1.y*wv1.y + hv1.z*wv1.z + hv1.w*wv1.w;
        }
    }

    zS[b0][r0] = a00; zS[b0][r1] = a01;
    zS[b1][r0] = a10; zS[b1][r1] = a11;
    __syncthreads();

    // gate update: thread u -> (b = u/8, el = u%8), e = e0+el
    const int b  = tid >> 3;
    const int el = tid & 7;
    const int e  = e0 + el;
    const float iv = zS[b][el];
    const float fv = zS[b][8 + el];
    const float gv = zS[b][16 + el];
    const float ov = zS[b][24 + el];
    const long long cidx = (long long)d * BATCH * HHD + b * HHD + e;
    const float cp = (s == 0) ? c0[cidx] : cbuf[cidx];
    const float si = 1.0f / (1.0f + expf(-iv));
    const float sf = 1.0f / (1.0f + expf(-fv));
    const float so = 1.0f / (1.0f + expf(-ov));
    const float cn = sf * cp + si * tanhf(gv);
    const float hn = so * tanhf(cn);
    cbuf[cidx] = cn;
    hdst[b * HHD + e] = hn;
    lstm_out[(long long)(t * BATCH + b) * 512 + d * HHD + e] = hn;
}

// ---------------------------------------------------------------------------
// Kernel 3: feats[b][t][tag] = lstm_out[t*32+b, :] . W_out[tag, :] + b_out[tag]
// One thread per (row, tag). 98304 threads.
// ---------------------------------------------------------------------------
__global__ __launch_bounds__(256) void feats_kernel(
    const float* __restrict__ lstm_out, const float* __restrict__ W_out,
    const float* __restrict__ b_out, float* __restrict__ feats)
{
    const int gid = blockIdx.x * 256 + threadIdx.x;
    if (gid >= 8192 * NTAGS) return;
    const int row = gid / NTAGS;
    const int tag = gid - row * NTAGS;
    const float4* x = (const float4*)(lstm_out + (long long)row * 512);
    const float4* w = (const float4*)(W_out + (long long)tag * 512);
    float acc = b_out[tag];
#pragma unroll 4
    for (int k = 0; k < 128; ++k) {
        float4 a = x[k], bw = w[k];
        acc += a.x * bw.x + a.y * bw.y + a.z * bw.z + a.w * bw.w;
    }
    const int t = row >> 5, b = row & 31;
    feats[(long long)b * (T_LEN * NTAGS) + t * NTAGS + tag] = acc;
}

// ---------------------------------------------------------------------------
// Kernel 4: Viterbi per batch. 32 WGs x 64 threads (1 wave).
// Lanes 0..11 each own a "next" tag; fv replicated in registers; bp in LDS.
// Outputs: out[b] = score (float), out[32 + b*256 + t] = path tag (as float).
// ---------------------------------------------------------------------------
__global__ __launch_bounds__(64) void viterbi_kernel(
    const float* __restrict__ feats, const float* __restrict__ trans,
    float* __restrict__ out)
{
    __shared__ float featS[T_LEN * NTAGS];       // 12 KB
    __shared__ float transS[NTAGS * NTAGS];
    __shared__ float fvS[NTAGS];
    __shared__ unsigned char bpS[T_LEN][NTAGS];  // 3 KB
    __shared__ float pathS[T_LEN];

    const int b = blockIdx.x;
    const int lane = threadIdx.x;

    { // stage feats row for this batch + transitions
        const float4* src = (const float4*)(feats + (long long)b * (T_LEN * NTAGS));
        float4* dst = (float4*)featS;
        for (int i = lane; i < (T_LEN * NTAGS) / 4; i += 64) dst[i] = src[i];
        for (int i = lane; i < NTAGS * NTAGS; i += 64) transS[i] = trans[i];
    }
    __syncthreads();

    float fv[NTAGS];
#pragma unroll
    for (int p = 0; p < NTAGS; ++p) fv[p] = (p == 10) ? 0.0f : NEGV;   // START_IDX=10

    for (int t = 0; t < T_LEN; ++t) {
        if (lane < NTAGS) {
            float best = -3.4e38f; int bi = 0;
#pragma unroll
            for (int p = 0; p < NTAGS; ++p) {
                const float v = fv[p] + transS[lane * NTAGS + p];
                if (v > best) { best = v; bi = p; }   // strict > : first max, matches argmax
            }
            bpS[t][lane] = (unsigned char)bi;
            fvS[lane] = best + featS[t * NTAGS + lane];
        }
        __syncthreads();
#pragma unroll
        for (int p = 0; p < NTAGS; ++p) fv[p] = fvS[p];
        __syncthreads();
    }

    if (lane < NTAGS) fvS[lane] = fv[lane] + transS[11 * NTAGS + lane];  // STOP_IDX=11
    __syncthreads();
    if (lane == 0) {
        float best = -3.4e38f; int bi = 0;
        for (int p = 0; p < NTAGS; ++p) {
            const float v = fvS[p];
            if (v > best) { best = v; bi = p; }
        }
        out[b] = best;               // score
        int cur = bi;
        pathS[T_LEN - 1] = (float)cur;
        for (int tt = T_LEN - 2; tt >= 0; --tt) {
            cur = bpS[tt + 1][cur];
            pathS[tt] = (float)cur;
        }
    }
    __syncthreads();
    float* po = out + BATCH + (long long)b * T_LEN;
    for (int i = lane; i < T_LEN; i += 64) po[i] = pathS[i];
}

// ---------------------------------------------------------------------------
extern "C" void kernel_launch(void* const* d_in, const int* in_sizes, int n_in,
                              void* d_out, int out_size, void* d_ws, size_t ws_size,
                              hipStream_t stream)
{
    (void)in_sizes; (void)n_in; (void)out_size; (void)ws_size;
    const int*   sentence = (const int*)  d_in[0];
    const float* embed    = (const float*)d_in[1];
    const float* W_ih_f   = (const float*)d_in[2];
    const float* W_hh_f   = (const float*)d_in[3];
    const float* b_f      = (const float*)d_in[4];
    const float* W_ih_b   = (const float*)d_in[5];
    const float* W_hh_b   = (const float*)d_in[6];
    const float* b_b      = (const float*)d_in[7];
    const float* W_out    = (const float*)d_in[8];
    const float* b_out    = (const float*)d_in[9];
    const float* trans    = (const float*)d_in[10];
    const float* h0       = (const float*)d_in[11];
    const float* c0       = (const float*)d_in[12];
    float* out = (float*)d_out;

    // workspace carve-up (all sizes 256B-aligned)
    char* ws = (char*)d_ws;
    float* zx       = (float*)ws; ws += (long long)8192 * 2048 * 4;   // 64 MB
    float* hbuf     = (float*)ws; ws += 2 * 2 * BATCH * HHD * 4;      // ping-pong h
    float* cbuf     = (float*)ws; ws += 2 * BATCH * HHD * 4;          // in-place c
    float* lstm_out = (float*)ws; ws += (long long)8192 * 512 * 4;    // 16 MB
    float* feats    = (float*)ws; ws += BATCH * T_LEN * NTAGS * 4;

    gemm_zx<<<1024, 256, 0, stream>>>(sentence, embed, W_ih_f, W_ih_b, b_f, b_b, zx);
    for (int s = 0; s < T_LEN; ++s)
        lstm_step<<<64, 256, 0, stream>>>(s, zx, W_hh_f, W_hh_b, h0, c0,
                                          hbuf, cbuf, lstm_out);
    feats_kernel<<<384, 256, 0, stream>>>(lstm_out, W_out, b_out, feats);
    viterbi_kernel<<<32, 64, 0, stream>>>(feats, trans, out);
}